// Round 9
// baseline (229.753 us; speedup 1.0000x reference)
//
#include <hip/hip_runtime.h>

// MinVarianceWeightsLayer: for each of B SPD 64x64 fp32 matrices S,
// solve S z = 1, output w = z / sum(z) as [B, 64, 1] fp32.
//
// ROUND-17: r14 structure (session best, ~192us bench) with two changes.
// (1) waves_per_eu(3,3) -> (3,6). The max=3 cap (carried since r13) limits
//     residency to 3 waves/SIMD (measured 2.25 avg) while the structure
//     has ~30us of exposed DS-round-trip + phase-1-chain latency that more
//     TLP would hide. min=3 keeps the 170-reg cap; 6-wave target (~85
//     regs) is above natural usage (~52-68) so no allocator squeeze.
//     (r16 lesson recorded: >128 live VGPRs is unreachable -- the
//     allocator pins at 128 and shuttles the rest through AGPRs; never
//     fight it again.)
// (2) Readlane slots pair their 8 scalar fmas into 4 v_pk_fma_f32 (the
//     broadcast pair u(j0),u(j1) sits in SGPRs; VOP3P reads one scalar
//     64-bit pair) -> RL slot 16 -> 12 instrs, ~960 instrs/wave saved.
// Everything else identical to r14: Gauss-Jordan, one wave/matrix, no
// barriers; dual-pipe rank-4 update split x=1/2 (calibrated: DS per-CU
// ~12cyc/b128 uniform, VALU per-SIMD ~3.7cyc/instr effective), A/B/C
// grouped prefetch (4 LDS + 4 RL slots per group); symmetric trailing
// block => published column value u_c(j) == el_c at lane j.
// Validated r9-r16: absmax 2.441e-4.

#define NN 64

typedef float v2f __attribute__((ext_vector_type(2)));
typedef float v4f __attribute__((ext_vector_type(4)));

template <int I> struct ic { static constexpr int value = I; };

template <int Start, int End, typename F>
__device__ __forceinline__ void static_for(F&& f) {
    if constexpr (Start < End) {
        f(ic<Start>{});
        static_for<Start + 1, End>(static_cast<F&&>(f));
    }
}

__device__ __forceinline__ float rlane(float v, int lane) {
    return __int_as_float(__builtin_amdgcn_readlane(__float_as_int(v), lane));
}

__device__ __forceinline__ float frcp(float x) {
#if __has_builtin(__builtin_amdgcn_rcpf)
    return __builtin_amdgcn_rcpf(x);   // ~1 ulp; plenty vs 2e-3 abs threshold
#else
    return 1.0f / x;
#endif
}

__device__ __forceinline__ v2f fma2(v2f a, v2f b, v2f c) {
#if __has_builtin(__builtin_elementwise_fma)
    return __builtin_elementwise_fma(a, b, c);   // -> v_pk_fma_f32
#else
    v2f r; r.x = fmaf(a.x, b.x, c.x); r.y = fmaf(a.y, b.y, c.y); return r;
#endif
}

__global__
__attribute__((amdgpu_flat_work_group_size(256, 256), amdgpu_waves_per_eu(3, 6)))
void minvar_kernel(const float* __restrict__ sigma,
                   float* __restrict__ out,
                   int batch) {
    // [wave][panel parity][ m*8 + c*2 + par ] : u_c[2m+par]
    __shared__ float pb[4][2][2 * NN * 4 / 2];   // 4 waves x 2 x 256 floats = 8 KB

    const int lane = threadIdx.x & 63;
    const int wid  = threadIdx.x >> 6;     // 4 waves/block, 1 matrix each
    const int bid  = blockIdx.x * 4 + wid;
    if (bid >= batch) return;              // no barriers anywhere -> safe

    const float* __restrict__ p = sigma + (size_t)bid * (NN * NN) + (size_t)lane * NN;

    // lane i's row as 32 float2 pairs (all indices compile-time -> VGPRs)
    v2f r[NN / 2];
    static_for<0, NN / 4>([&](auto j4c) {
        constexpr int j4 = decltype(j4c)::value;
        v4f v = reinterpret_cast<const v4f*>(p)[j4];
        r[2 * j4 + 0] = v2f{v.x, v.y};
        r[2 * j4 + 1] = v2f{v.z, v.w};
    });

    float b = 1.0f;                        // RHS: ones
    float d = 1.0f;                        // this lane's pivot (set exactly once)
    const int wbase = (lane >> 1) * 8 + (lane & 1);   // scatter-write index

    static_for<0, 16>([&](auto pc) {
        constexpr int P  = decltype(pc)::value;
        constexpr int k0 = 4 * P;
        constexpr int m0 = 2 * P;          // pair-slots m0, m0+1 are the panel
        float* __restrict__ wb = &pb[wid][P & 1][0];

        // ---- phase 1: in-panel Jordan elimination (readlane only, local) ----
        const float el0  = r[m0].x;                    // A[i][k0] (pre-panel)
        if constexpr (P < 15) wb[wbase + 0] = el0;     // publish early
        const float piv0 = rlane(el0, k0);
        const float nf0  = (lane != k0) ? (-el0 * frcp(piv0)) : 0.0f;
        d = (lane == k0) ? el0 : d;
        b = fmaf(nf0, rlane(b, k0), b);
        const float u01 = rlane(r[m0].y,     k0);
        const float u02 = rlane(r[m0 + 1].x, k0);
        const float u03 = rlane(r[m0 + 1].y, k0);
        r[m0].y     = fmaf(nf0, u01, r[m0].y);
        r[m0 + 1].x = fmaf(nf0, u02, r[m0 + 1].x);
        r[m0 + 1].y = fmaf(nf0, u03, r[m0 + 1].y);

        const float el1  = r[m0].y;                    // A[i][k0+1] after c0
        if constexpr (P < 15) wb[wbase + 2] = el1;
        const float piv1 = rlane(el1, k0 + 1);
        const float nf1  = (lane != k0 + 1) ? (-el1 * frcp(piv1)) : 0.0f;
        d = (lane == k0 + 1) ? el1 : d;
        b = fmaf(nf1, rlane(b, k0 + 1), b);
        const float u12 = rlane(r[m0 + 1].x, k0 + 1);
        const float u13 = rlane(r[m0 + 1].y, k0 + 1);
        r[m0 + 1].x = fmaf(nf1, u12, r[m0 + 1].x);
        r[m0 + 1].y = fmaf(nf1, u13, r[m0 + 1].y);

        const float el2  = r[m0 + 1].x;                // A[i][k0+2] after c0,c1
        if constexpr (P < 15) wb[wbase + 4] = el2;
        const float piv2 = rlane(el2, k0 + 2);
        const float nf2  = (lane != k0 + 2) ? (-el2 * frcp(piv2)) : 0.0f;
        d = (lane == k0 + 2) ? el2 : d;
        b = fmaf(nf2, rlane(b, k0 + 2), b);
        const float u23 = rlane(r[m0 + 1].y, k0 + 2);
        r[m0 + 1].y = fmaf(nf2, u23, r[m0 + 1].y);

        const float el3  = r[m0 + 1].y;                // A[i][k0+3] after c0..c2
        if constexpr (P < 15) wb[wbase + 6] = el3;
        const float piv3 = rlane(el3, k0 + 3);
        const float nf3  = (lane != k0 + 3) ? (-el3 * frcp(piv3)) : 0.0f;
        d = (lane == k0 + 3) ? el3 : d;
        b = fmaf(nf3, rlane(b, k0 + 3), b);

        if constexpr (P < 15) {
            // ---- phase 3: rank-4 update, pipelined dual-pipe, x = 1/2 ----
            // Groups of 8 trailing slots: 4 LDS-prefetch + 4 readlane.
            const v2f n0 = v2f{nf0, nf0}, n1 = v2f{nf1, nf1};
            const v2f n2 = v2f{nf2, nf2}, n3 = v2f{nf3, nf3};
            static_for<0, 4>([&](auto gc) {
                constexpr int G = decltype(gc)::value;
                constexpr int s = m0 + 2 + 8 * G;
                if constexpr (s < NN / 2) {
                    constexpr int e = (s + 8 < NN / 2) ? (s + 8) : (NN / 2);
                    v4f lo[4], hi[4];
                    // pass A: issue DS reads for LDS slots (q = 0..3)
                    static_for<s, e>([&](auto mc) {
                        constexpr int m = decltype(mc)::value;
                        constexpr int q = m - s;
                        if constexpr (q < 4) {
                            lo[q] = *reinterpret_cast<const v4f*>(wb + 8 * m);
                            hi[q] = *reinterpret_cast<const v4f*>(wb + 8 * m + 4);
                        }
                    });
                    // pass B: readlane slots (q = 4..7) — independent of DS.
                    // Broadcast pair u(j0),u(j1) lives in SGPRs; paired into
                    // v_pk_fma_f32 (scalar-pair source) -> 12 instrs/slot.
                    static_for<s, e>([&](auto mc) {
                        constexpr int m = decltype(mc)::value;
                        constexpr int q = m - s;
                        if constexpr (q >= 4) {
                            constexpr int j0 = 2 * m, j1 = 2 * m + 1;
                            const float u00 = rlane(el0, j0), u01_ = rlane(el0, j1);
                            const float u10 = rlane(el1, j0), u11_ = rlane(el1, j1);
                            const float u20 = rlane(el2, j0), u21_ = rlane(el2, j1);
                            const float u30 = rlane(el3, j0), u31_ = rlane(el3, j1);
                            v2f acc = r[m];
                            acc = fma2(n0, v2f{u00, u01_}, acc);
                            acc = fma2(n1, v2f{u10, u11_}, acc);
                            acc = fma2(n2, v2f{u20, u21_}, acc);
                            acc = fma2(n3, v2f{u30, u31_}, acc);
                            r[m] = acc;
                        }
                    });
                    // pass C: consume prefetched LDS data
                    static_for<s, e>([&](auto mc) {
                        constexpr int m = decltype(mc)::value;
                        constexpr int q = m - s;
                        if constexpr (q < 4) {
                            v2f acc = r[m];
                            acc = fma2(n0, v2f{lo[q].x, lo[q].y}, acc);
                            acc = fma2(n1, v2f{lo[q].z, lo[q].w}, acc);
                            acc = fma2(n2, v2f{hi[q].x, hi[q].y}, acc);
                            acc = fma2(n3, v2f{hi[q].z, hi[q].w}, acc);
                            r[m] = acc;
                        }
                    });
                }
            });
        }
    });

    // ---- diagonal system: z = b / d (no back-substitution in Gauss-Jordan) ----
    const float z = b * frcp(d);

    // ---- normalize: w = z / sum(z) ----
    float tot = z;
    #pragma unroll
    for (int off = 32; off >= 1; off >>= 1)
        tot += __shfl_xor(tot, off, 64);

    out[(size_t)bid * NN + lane] = z * frcp(tot);
}

extern "C" void kernel_launch(void* const* d_in, const int* in_sizes, int n_in,
                              void* d_out, int out_size, void* d_ws, size_t ws_size,
                              hipStream_t stream) {
    const float* sigma = (const float*)d_in[0];
    float* out = (float*)d_out;
    const int batch  = in_sizes[0] / (NN * NN);   // 8192
    const int blocks = (batch + 3) / 4;           // 4 matrices per 256-thr block
    minvar_kernel<<<blocks, 256, 0, stream>>>(sigma, out, batch);
}

// Round 10
// 196.830 us; speedup vs baseline: 1.1673x; 1.1673x over previous
//
#include <hip/hip_runtime.h>

// MinVarianceWeightsLayer: for each of B SPD 64x64 fp32 matrices S,
// solve S z = 1, output w = z / sum(z) as [B, 64, 1] fp32.
//
// ROUND-18: r14 structure byte-identical, ONLY waves_per_eu(3,3) -> (4,4).
// Occupancy-knob history on this structure:
//   no-cap/(3,6): scheduler targets high waves -> squeezes VGPR to 40-52,
//     AGPR shuttles in every chain, slow (r10/r17; r17 also tripled FETCH
//     via L1 thrash of the stride-256B row loads).
//   (3,3): VGPR 68, ~2.25-3 waves/SIMD, kernel ~70us -- session best (r14).
//   (2,2): allocator pins 128 + shuttles ~100 floats through AGPRs (r16).
// (4,4) is the untested cell: 128-reg budget is ABOVE the 68 the allocator
// naturally picks under (3,3) (no new squeeze pressure), while the
// residency cap rises 3->4 waves/SIMD = +33% TLP against the ~30us of
// exposed DS-round-trip + phase-1-chain latency that r15 proved cannot be
// hidden intra-wave. Last clean single-variable probe on this structure.
// Algorithm (validated r9-r17, absmax 2.441e-4): Gauss-Jordan, one wave
// per matrix, no barriers. Dual-pipe rank-4 trailing update, split x=1/2
// (calibrated: DS per-CU ~12cyc/uniform b128, VALU per-SIMD ~3.7cyc/instr):
// per group of 8 slots, {issue 4 slots' ds_read_b128} -> {4 readlane
// slots cover the DS latency} -> {consume prefetched}. Symmetric trailing
// block => published column value u_c(j) == el_c at lane j.

#define NN 64

typedef float v2f __attribute__((ext_vector_type(2)));
typedef float v4f __attribute__((ext_vector_type(4)));

template <int I> struct ic { static constexpr int value = I; };

template <int Start, int End, typename F>
__device__ __forceinline__ void static_for(F&& f) {
    if constexpr (Start < End) {
        f(ic<Start>{});
        static_for<Start + 1, End>(static_cast<F&&>(f));
    }
}

__device__ __forceinline__ float rlane(float v, int lane) {
    return __int_as_float(__builtin_amdgcn_readlane(__float_as_int(v), lane));
}

__device__ __forceinline__ float frcp(float x) {
#if __has_builtin(__builtin_amdgcn_rcpf)
    return __builtin_amdgcn_rcpf(x);   // ~1 ulp; plenty vs 2e-3 abs threshold
#else
    return 1.0f / x;
#endif
}

__device__ __forceinline__ v2f fma2(v2f a, v2f b, v2f c) {
#if __has_builtin(__builtin_elementwise_fma)
    return __builtin_elementwise_fma(a, b, c);   // -> v_pk_fma_f32
#else
    v2f r; r.x = fmaf(a.x, b.x, c.x); r.y = fmaf(a.y, b.y, c.y); return r;
#endif
}

__global__
__attribute__((amdgpu_flat_work_group_size(256, 256), amdgpu_waves_per_eu(4, 4)))
void minvar_kernel(const float* __restrict__ sigma,
                   float* __restrict__ out,
                   int batch) {
    // [wave][panel parity][ m*8 + c*2 + par ] : u_c[2m+par]
    __shared__ float pb[4][2][2 * NN * 4 / 2];   // 4 waves x 2 x 256 floats = 8 KB

    const int lane = threadIdx.x & 63;
    const int wid  = threadIdx.x >> 6;     // 4 waves/block, 1 matrix each
    const int bid  = blockIdx.x * 4 + wid;
    if (bid >= batch) return;              // no barriers anywhere -> safe

    const float* __restrict__ p = sigma + (size_t)bid * (NN * NN) + (size_t)lane * NN;

    // lane i's row as 32 float2 pairs (all indices compile-time -> VGPRs)
    v2f r[NN / 2];
    static_for<0, NN / 4>([&](auto j4c) {
        constexpr int j4 = decltype(j4c)::value;
        v4f v = reinterpret_cast<const v4f*>(p)[j4];
        r[2 * j4 + 0] = v2f{v.x, v.y};
        r[2 * j4 + 1] = v2f{v.z, v.w};
    });

    float b = 1.0f;                        // RHS: ones
    float d = 1.0f;                        // this lane's pivot (set exactly once)
    const int wbase = (lane >> 1) * 8 + (lane & 1);   // scatter-write index

    static_for<0, 16>([&](auto pc) {
        constexpr int P  = decltype(pc)::value;
        constexpr int k0 = 4 * P;
        constexpr int m0 = 2 * P;          // pair-slots m0, m0+1 are the panel
        float* __restrict__ wb = &pb[wid][P & 1][0];

        // ---- phase 1: in-panel Jordan elimination (readlane only, local) ----
        const float el0  = r[m0].x;                    // A[i][k0] (pre-panel)
        if constexpr (P < 15) wb[wbase + 0] = el0;     // publish early
        const float piv0 = rlane(el0, k0);
        const float nf0  = (lane != k0) ? (-el0 * frcp(piv0)) : 0.0f;
        d = (lane == k0) ? el0 : d;
        b = fmaf(nf0, rlane(b, k0), b);
        const float u01 = rlane(r[m0].y,     k0);
        const float u02 = rlane(r[m0 + 1].x, k0);
        const float u03 = rlane(r[m0 + 1].y, k0);
        r[m0].y     = fmaf(nf0, u01, r[m0].y);
        r[m0 + 1].x = fmaf(nf0, u02, r[m0 + 1].x);
        r[m0 + 1].y = fmaf(nf0, u03, r[m0 + 1].y);

        const float el1  = r[m0].y;                    // A[i][k0+1] after c0
        if constexpr (P < 15) wb[wbase + 2] = el1;
        const float piv1 = rlane(el1, k0 + 1);
        const float nf1  = (lane != k0 + 1) ? (-el1 * frcp(piv1)) : 0.0f;
        d = (lane == k0 + 1) ? el1 : d;
        b = fmaf(nf1, rlane(b, k0 + 1), b);
        const float u12 = rlane(r[m0 + 1].x, k0 + 1);
        const float u13 = rlane(r[m0 + 1].y, k0 + 1);
        r[m0 + 1].x = fmaf(nf1, u12, r[m0 + 1].x);
        r[m0 + 1].y = fmaf(nf1, u13, r[m0 + 1].y);

        const float el2  = r[m0 + 1].x;                // A[i][k0+2] after c0,c1
        if constexpr (P < 15) wb[wbase + 4] = el2;
        const float piv2 = rlane(el2, k0 + 2);
        const float nf2  = (lane != k0 + 2) ? (-el2 * frcp(piv2)) : 0.0f;
        d = (lane == k0 + 2) ? el2 : d;
        b = fmaf(nf2, rlane(b, k0 + 2), b);
        const float u23 = rlane(r[m0 + 1].y, k0 + 2);
        r[m0 + 1].y = fmaf(nf2, u23, r[m0 + 1].y);

        const float el3  = r[m0 + 1].y;                // A[i][k0+3] after c0..c2
        if constexpr (P < 15) wb[wbase + 6] = el3;
        const float piv3 = rlane(el3, k0 + 3);
        const float nf3  = (lane != k0 + 3) ? (-el3 * frcp(piv3)) : 0.0f;
        d = (lane == k0 + 3) ? el3 : d;
        b = fmaf(nf3, rlane(b, k0 + 3), b);

        if constexpr (P < 15) {
            // ---- phase 3: rank-4 update, pipelined dual-pipe, x = 1/2 ----
            // Groups of 8 trailing slots: 4 LDS-prefetch + 4 readlane.
            const v2f n0 = v2f{nf0, nf0}, n1 = v2f{nf1, nf1};
            const v2f n2 = v2f{nf2, nf2}, n3 = v2f{nf3, nf3};
            static_for<0, 4>([&](auto gc) {
                constexpr int G = decltype(gc)::value;
                constexpr int s = m0 + 2 + 8 * G;
                if constexpr (s < NN / 2) {
                    constexpr int e = (s + 8 < NN / 2) ? (s + 8) : (NN / 2);
                    v4f lo[4], hi[4];
                    // pass A: issue DS reads for LDS slots (q = 0..3)
                    static_for<s, e>([&](auto mc) {
                        constexpr int m = decltype(mc)::value;
                        constexpr int q = m - s;
                        if constexpr (q < 4) {
                            lo[q] = *reinterpret_cast<const v4f*>(wb + 8 * m);
                            hi[q] = *reinterpret_cast<const v4f*>(wb + 8 * m + 4);
                        }
                    });
                    // pass B: readlane slots (q = 4..7) — independent of DS,
                    // ~240 VALU cycles covering the DS round-trip latency
                    static_for<s, e>([&](auto mc) {
                        constexpr int m = decltype(mc)::value;
                        constexpr int q = m - s;
                        if constexpr (q >= 4) {
                            constexpr int j0 = 2 * m, j1 = 2 * m + 1;
                            float ax = r[m].x, ay = r[m].y;
                            ax = fmaf(nf0, rlane(el0, j0), ax);
                            ay = fmaf(nf0, rlane(el0, j1), ay);
                            ax = fmaf(nf1, rlane(el1, j0), ax);
                            ay = fmaf(nf1, rlane(el1, j1), ay);
                            ax = fmaf(nf2, rlane(el2, j0), ax);
                            ay = fmaf(nf2, rlane(el2, j1), ay);
                            ax = fmaf(nf3, rlane(el3, j0), ax);
                            ay = fmaf(nf3, rlane(el3, j1), ay);
                            r[m] = v2f{ax, ay};
                        }
                    });
                    // pass C: consume prefetched LDS data
                    static_for<s, e>([&](auto mc) {
                        constexpr int m = decltype(mc)::value;
                        constexpr int q = m - s;
                        if constexpr (q < 4) {
                            v2f acc = r[m];
                            acc = fma2(n0, v2f{lo[q].x, lo[q].y}, acc);
                            acc = fma2(n1, v2f{lo[q].z, lo[q].w}, acc);
                            acc = fma2(n2, v2f{hi[q].x, hi[q].y}, acc);
                            acc = fma2(n3, v2f{hi[q].z, hi[q].w}, acc);
                            r[m] = acc;
                        }
                    });
                }
            });
        }
    });

    // ---- diagonal system: z = b / d (no back-substitution in Gauss-Jordan) ----
    const float z = b * frcp(d);

    // ---- normalize: w = z / sum(z) ----
    float tot = z;
    #pragma unroll
    for (int off = 32; off >= 1; off >>= 1)
        tot += __shfl_xor(tot, off, 64);

    out[(size_t)bid * NN + lane] = z * frcp(tot);
}

extern "C" void kernel_launch(void* const* d_in, const int* in_sizes, int n_in,
                              void* d_out, int out_size, void* d_ws, size_t ws_size,
                              hipStream_t stream) {
    const float* sigma = (const float*)d_in[0];
    float* out = (float*)d_out;
    const int batch  = in_sizes[0] / (NN * NN);   // 8192
    const int blocks = (batch + 3) / 4;           // 4 matrices per 256-thr block
    minvar_kernel<<<blocks, 256, 0, stream>>>(sigma, out, batch);
}

// Round 11
// 194.350 us; speedup vs baseline: 1.1822x; 1.0128x over previous
//
#include <hip/hip_runtime.h>

// MinVarianceWeightsLayer: for each of B SPD 64x64 fp32 matrices S,
// solve S z = 1, output w = z / sum(z) as [B, 64, 1] fp32.
//
// ROUND-19: r14 structure + (3,3) (proven optimal occupancy cell across
// r10-r18) + CONFLICT-REDUCED publish layout. The 15x4 publish writes were
// 8-way bank-conflicted (slot stride 8 floats -> 32 lane-pairs over 4 bank
// classes; measured SQ_LDS_BANK_CONFLICT = 2,949,120 = 15*4*8192*6 extra
// cycles = ~11.5k wasted DS cycles/CU). Fix: pad 16B every 4 slots --
// slot_base(m) = 8m + 4*(m>>2) floats. Write banks (12q+8r) mod 32 ->
// 4-way instead of 8-way (4-way is the floor while keeping 16B-aligned
// ds_read_b128 slots; 8B slots would double DS op count). Reads unchanged:
// 2 uniform ds_read_b128 per slot, broadcast, conflict-free.
// Everything else byte-identical to r14: Gauss-Jordan, one wave/matrix,
// no barriers; dual-pipe rank-4 trailing update split x=1/2 (calibrated
// DS ~12cyc/uniform-b128 per CU, VALU ~3.7cyc/instr per SIMD); groups of
// 8 slots = {issue 4 slots' DS reads} -> {4 readlane slots cover the DS
// latency} -> {consume prefetched}; symmetric trailing block => published
// column value u_c(j) == el_c at lane j. Validated absmax 2.441e-4.
// Ceiling note: VALU ~40us/SIMD || DS ~38us/CU, measured ~70us kernel;
// the ~30us overlap gap resisted rounds 12-18 (allocator caps TLP at
// ~2.25-3 waves/SIMD, intra-wave ILP exhausted). This is the last
// positive-EV lever on this structure.

#define NN 64

typedef float v2f __attribute__((ext_vector_type(2)));
typedef float v4f __attribute__((ext_vector_type(4)));

template <int I> struct ic { static constexpr int value = I; };

template <int Start, int End, typename F>
__device__ __forceinline__ void static_for(F&& f) {
    if constexpr (Start < End) {
        f(ic<Start>{});
        static_for<Start + 1, End>(static_cast<F&&>(f));
    }
}

__device__ __forceinline__ float rlane(float v, int lane) {
    return __int_as_float(__builtin_amdgcn_readlane(__float_as_int(v), lane));
}

__device__ __forceinline__ float frcp(float x) {
#if __has_builtin(__builtin_amdgcn_rcpf)
    return __builtin_amdgcn_rcpf(x);   // ~1 ulp; plenty vs 2e-3 abs threshold
#else
    return 1.0f / x;
#endif
}

__device__ __forceinline__ v2f fma2(v2f a, v2f b, v2f c) {
#if __has_builtin(__builtin_elementwise_fma)
    return __builtin_elementwise_fma(a, b, c);   // -> v_pk_fma_f32
#else
    v2f r; r.x = fmaf(a.x, b.x, c.x); r.y = fmaf(a.y, b.y, c.y); return r;
#endif
}

// slot m (pair-slot index 0..31) base offset in floats: 8m + 16B pad per 4 slots
#define SLOT_BASE(m) (8 * (m) + 4 * ((m) >> 2))
#define PBSZ (8 * 32 + 4 * 8)   // 288 floats per buffer

__global__
__attribute__((amdgpu_flat_work_group_size(256, 256), amdgpu_waves_per_eu(3, 3)))
void minvar_kernel(const float* __restrict__ sigma,
                   float* __restrict__ out,
                   int batch) {
    // [wave][panel parity][ SLOT_BASE(m) + c*2 + par ] : u_c[2m+par]
    __shared__ float pb[4][2][PBSZ];   // 4 waves x 2 x 288 floats ~= 9.2 KB

    const int lane = threadIdx.x & 63;
    const int wid  = threadIdx.x >> 6;     // 4 waves/block, 1 matrix each
    const int bid  = blockIdx.x * 4 + wid;
    if (bid >= batch) return;              // no barriers anywhere -> safe

    const float* __restrict__ p = sigma + (size_t)bid * (NN * NN) + (size_t)lane * NN;

    // lane i's row as 32 float2 pairs (all indices compile-time -> VGPRs)
    v2f r[NN / 2];
    static_for<0, NN / 4>([&](auto j4c) {
        constexpr int j4 = decltype(j4c)::value;
        v4f v = reinterpret_cast<const v4f*>(p)[j4];
        r[2 * j4 + 0] = v2f{v.x, v.y};
        r[2 * j4 + 1] = v2f{v.z, v.w};
    });

    float b = 1.0f;                        // RHS: ones
    float d = 1.0f;                        // this lane's pivot (set exactly once)
    // scatter-write index: padded slot base + parity
    const int mIdx  = lane >> 1;
    const int wbase = 8 * mIdx + 4 * (mIdx >> 2) + (lane & 1);

    static_for<0, 16>([&](auto pc) {
        constexpr int P  = decltype(pc)::value;
        constexpr int k0 = 4 * P;
        constexpr int m0 = 2 * P;          // pair-slots m0, m0+1 are the panel
        float* __restrict__ wb = &pb[wid][P & 1][0];

        // ---- phase 1: in-panel Jordan elimination (readlane only, local) ----
        const float el0  = r[m0].x;                    // A[i][k0] (pre-panel)
        if constexpr (P < 15) wb[wbase + 0] = el0;     // publish early
        const float piv0 = rlane(el0, k0);
        const float nf0  = (lane != k0) ? (-el0 * frcp(piv0)) : 0.0f;
        d = (lane == k0) ? el0 : d;
        b = fmaf(nf0, rlane(b, k0), b);
        const float u01 = rlane(r[m0].y,     k0);
        const float u02 = rlane(r[m0 + 1].x, k0);
        const float u03 = rlane(r[m0 + 1].y, k0);
        r[m0].y     = fmaf(nf0, u01, r[m0].y);
        r[m0 + 1].x = fmaf(nf0, u02, r[m0 + 1].x);
        r[m0 + 1].y = fmaf(nf0, u03, r[m0 + 1].y);

        const float el1  = r[m0].y;                    // A[i][k0+1] after c0
        if constexpr (P < 15) wb[wbase + 2] = el1;
        const float piv1 = rlane(el1, k0 + 1);
        const float nf1  = (lane != k0 + 1) ? (-el1 * frcp(piv1)) : 0.0f;
        d = (lane == k0 + 1) ? el1 : d;
        b = fmaf(nf1, rlane(b, k0 + 1), b);
        const float u12 = rlane(r[m0 + 1].x, k0 + 1);
        const float u13 = rlane(r[m0 + 1].y, k0 + 1);
        r[m0 + 1].x = fmaf(nf1, u12, r[m0 + 1].x);
        r[m0 + 1].y = fmaf(nf1, u13, r[m0 + 1].y);

        const float el2  = r[m0 + 1].x;                // A[i][k0+2] after c0,c1
        if constexpr (P < 15) wb[wbase + 4] = el2;
        const float piv2 = rlane(el2, k0 + 2);
        const float nf2  = (lane != k0 + 2) ? (-el2 * frcp(piv2)) : 0.0f;
        d = (lane == k0 + 2) ? el2 : d;
        b = fmaf(nf2, rlane(b, k0 + 2), b);
        const float u23 = rlane(r[m0 + 1].y, k0 + 2);
        r[m0 + 1].y = fmaf(nf2, u23, r[m0 + 1].y);

        const float el3  = r[m0 + 1].y;                // A[i][k0+3] after c0..c2
        if constexpr (P < 15) wb[wbase + 6] = el3;
        const float piv3 = rlane(el3, k0 + 3);
        const float nf3  = (lane != k0 + 3) ? (-el3 * frcp(piv3)) : 0.0f;
        d = (lane == k0 + 3) ? el3 : d;
        b = fmaf(nf3, rlane(b, k0 + 3), b);

        if constexpr (P < 15) {
            // ---- phase 3: rank-4 update, pipelined dual-pipe, x = 1/2 ----
            // Groups of 8 trailing slots: 4 LDS-prefetch + 4 readlane.
            const v2f n0 = v2f{nf0, nf0}, n1 = v2f{nf1, nf1};
            const v2f n2 = v2f{nf2, nf2}, n3 = v2f{nf3, nf3};
            static_for<0, 4>([&](auto gc) {
                constexpr int G = decltype(gc)::value;
                constexpr int s = m0 + 2 + 8 * G;
                if constexpr (s < NN / 2) {
                    constexpr int e = (s + 8 < NN / 2) ? (s + 8) : (NN / 2);
                    v4f lo[4], hi[4];
                    // pass A: issue DS reads for LDS slots (q = 0..3)
                    static_for<s, e>([&](auto mc) {
                        constexpr int m = decltype(mc)::value;
                        constexpr int q = m - s;
                        if constexpr (q < 4) {
                            constexpr int sb = SLOT_BASE(m);
                            lo[q] = *reinterpret_cast<const v4f*>(wb + sb);
                            hi[q] = *reinterpret_cast<const v4f*>(wb + sb + 4);
                        }
                    });
                    // pass B: readlane slots (q = 4..7) — independent of DS,
                    // ~240 VALU cycles covering the DS round-trip latency
                    static_for<s, e>([&](auto mc) {
                        constexpr int m = decltype(mc)::value;
                        constexpr int q = m - s;
                        if constexpr (q >= 4) {
                            constexpr int j0 = 2 * m, j1 = 2 * m + 1;
                            float ax = r[m].x, ay = r[m].y;
                            ax = fmaf(nf0, rlane(el0, j0), ax);
                            ay = fmaf(nf0, rlane(el0, j1), ay);
                            ax = fmaf(nf1, rlane(el1, j0), ax);
                            ay = fmaf(nf1, rlane(el1, j1), ay);
                            ax = fmaf(nf2, rlane(el2, j0), ax);
                            ay = fmaf(nf2, rlane(el2, j1), ay);
                            ax = fmaf(nf3, rlane(el3, j0), ax);
                            ay = fmaf(nf3, rlane(el3, j1), ay);
                            r[m] = v2f{ax, ay};
                        }
                    });
                    // pass C: consume prefetched LDS data
                    static_for<s, e>([&](auto mc) {
                        constexpr int m = decltype(mc)::value;
                        constexpr int q = m - s;
                        if constexpr (q < 4) {
                            v2f acc = r[m];
                            acc = fma2(n0, v2f{lo[q].x, lo[q].y}, acc);
                            acc = fma2(n1, v2f{lo[q].z, lo[q].w}, acc);
                            acc = fma2(n2, v2f{hi[q].x, hi[q].y}, acc);
                            acc = fma2(n3, v2f{hi[q].z, hi[q].w}, acc);
                            r[m] = acc;
                        }
                    });
                }
            });
        }
    });

    // ---- diagonal system: z = b / d (no back-substitution in Gauss-Jordan) ----
    const float z = b * frcp(d);

    // ---- normalize: w = z / sum(z) ----
    float tot = z;
    #pragma unroll
    for (int off = 32; off >= 1; off >>= 1)
        tot += __shfl_xor(tot, off, 64);

    out[(size_t)bid * NN + lane] = z * frcp(tot);
}

extern "C" void kernel_launch(void* const* d_in, const int* in_sizes, int n_in,
                              void* d_out, int out_size, void* d_ws, size_t ws_size,
                              hipStream_t stream) {
    const float* sigma = (const float*)d_in[0];
    float* out = (float*)d_out;
    const int batch  = in_sizes[0] / (NN * NN);   // 8192
    const int blocks = (batch + 3) / 4;           // 4 matrices per 256-thr block
    minvar_kernel<<<blocks, 256, 0, stream>>>(sigma, out, batch);
}